// Round 1
// baseline (514.904 us; speedup 1.0000x reference)
//
#include <hip/hip_runtime.h>
#include <hip/hip_fp16.h>
#include <math.h>

#define FDIM  128
#define L1OUT 16
#define L2DIM 17
#define TRM   128     // f-rows per block in node_transform (MFMA version)
#define HSTR  136     // LDS tile row stride in halves (272 B: 2-way-only conflicts)

typedef _Float16 f16x8 __attribute__((ext_vector_type(8)));   // MFMA A/B frag (4 VGPR)
typedef float    f32x4 __attribute__((ext_vector_type(4)));   // MFMA C/D frag

// one 32-byte fp16 node row (16 halves); align 16 -> 2x global_load_dwordx4
struct __align__(16) H16 { __half2 h[8]; };

__device__ __forceinline__ float lrelu(float v) { return v >= 0.f ? v : 0.1f * v; }

// ============================================================================
// K1 (MFMA): [A|B] = f @ W'  where W'[k][c] = W1[k][c] (c<16) / W1[128+k][c-16].
// M=100k, K=128, N=32 -> mfma_f32_16x16x32_f16, 2 N-tiles (nt=0 -> A, 1 -> B).
// R8 lesson: VALU version needs 256 uniform ds_read_b128/wave for W1 (~35 us
// LDS-pipe floor). MFMA holds W' frags in 32 VGPRs (loaded once/block from
// L2-hot W1) and reads f-frags as 8 ds_read_b128/wave/subtile -> ~20x fewer
// LDS ops. f staged as fp16 (A/B outputs were already fp16; error budget ok).
// Layouts (HW-verified per guide): A-frag A[m=lane&15][k=(lane>>4)*8+j];
// B-frag B[k=(lane>>4)*8+j][n=lane&15]; C/D col=lane&15, row=(lane>>4)*4+reg.
// + degree atomics folded in (deg zeroed by memsetAsync before this kernel).
// ============================================================================
__global__ void node_transform(
    const float* __restrict__ f, const float* __restrict__ W1,
    const float* __restrict__ b1,
    const int* __restrict__ ind_i, const float* __restrict__ val,
    H16* __restrict__ A, H16* __restrict__ B,
    float* __restrict__ deg, int N, int E)
{
    __shared__ __align__(16) _Float16 tile[TRM * HSTR];   // 34.8 KB

    const int t    = threadIdx.x;
    const int gtid = blockIdx.x * 256 + t;
    const int GT   = gridDim.x * 256;

    // ---- degree atomics (4 edges/thread, grid-stride, fire-and-forget) ----
    {
        const int E4 = E >> 2;
        for (int q = gtid; q < E4; q += GT) {
            int e = q << 2;
            int4   ii = *reinterpret_cast<const int4*>(ind_i + e);
            float4 vv = *reinterpret_cast<const float4*>(val + e);
            atomicAdd(&deg[ii.x], fabsf(vv.x));
            atomicAdd(&deg[ii.y], fabsf(vv.y));
            atomicAdd(&deg[ii.z], fabsf(vv.z));
            atomicAdd(&deg[ii.w], fabsf(vv.w));
        }
        if (gtid < (E & 3)) {
            int e = (E & ~3) + gtid;
            atomicAdd(&deg[ind_i[e]], fabsf(val[e]));
        }
    }

    const int lane = t & 63;
    const int wv   = t >> 6;          // wave 0..3
    const int n    = lane & 15;       // MFMA matrix-dim index (col)
    const int quad = lane >> 4;       // k-block / row-group selector

    // ---- load W' B-frags once per block: bfr[nt][ks], k = 32*ks + 8*quad + j
    f16x8 bfr[2][4];
#pragma unroll
    for (int nt = 0; nt < 2; ++nt)
#pragma unroll
        for (int ks = 0; ks < 4; ++ks) {
            f16x8 bf;
#pragma unroll
            for (int j = 0; j < 8; ++j) {
                int k = 32 * ks + 8 * quad + j;
                bf[j] = (_Float16)W1[(size_t)(nt * FDIM + k) * L1OUT + n];
            }
            bfr[nt][ks] = bf;
        }
    float b1v = b1[n];                // folded into nt=0 accumulator init

    // ---- stage 128 f-rows as fp16 into padded LDS tile (coalesced) ----
    const int base = blockIdx.x * TRM;
#pragma unroll
    for (int q = 0; q < 8; ++q) {
        int p  = t + 256 * q;         // half8-chunk index 0..2047
        int r  = p >> 4;              // 16 chunks per row
        int c8 = p & 15;              // chunk within row (8 halves)
        float4 lo = make_float4(0.f, 0.f, 0.f, 0.f);
        float4 hi = lo;
        if (base + r < N) {
            const float4* src = reinterpret_cast<const float4*>(
                f + (size_t)(base + r) * FDIM + c8 * 8);
            lo = src[0];
            hi = src[1];
        }
        f16x8 hx;
        hx[0] = (_Float16)lo.x; hx[1] = (_Float16)lo.y;
        hx[2] = (_Float16)lo.z; hx[3] = (_Float16)lo.w;
        hx[4] = (_Float16)hi.x; hx[5] = (_Float16)hi.y;
        hx[6] = (_Float16)hi.z; hx[7] = (_Float16)hi.w;
        *reinterpret_cast<f16x8*>(&tile[r * HSTR + c8 * 8]) = hx;
    }
    __syncthreads();

    // ---- compute: wave wv handles M-subtiles wv and wv+4 (16 rows each) ----
#pragma unroll
    for (int si = 0; si < 2; ++si) {
        const int m0 = (wv + 4 * si) * 16;
        f32x4 acc0 = { b1v, b1v, b1v, b1v };      // A-cols + b1
        f32x4 acc1 = { 0.f, 0.f, 0.f, 0.f };      // B-cols
#pragma unroll
        for (int ks = 0; ks < 4; ++ks) {
            // A-frag: row m0+n, k = 32*ks + 8*quad .. +7  (one ds_read_b128)
            f16x8 af = *reinterpret_cast<const f16x8*>(
                &tile[(m0 + n) * HSTR + 32 * ks + 8 * quad]);
            acc0 = __builtin_amdgcn_mfma_f32_16x16x32_f16(af, bfr[0][ks], acc0, 0, 0, 0);
            acc1 = __builtin_amdgcn_mfma_f32_16x16x32_f16(af, bfr[1][ks], acc1, 0, 0, 0);
        }
        // epilogue: D col = n, rows = m0 + quad*4 + reg
#pragma unroll
        for (int reg = 0; reg < 4; ++reg) {
            int node = base + m0 + quad * 4 + reg;
            if (node < N) {
                reinterpret_cast<_Float16*>(A + node)[n] = (_Float16)acc0[reg];
                reinterpret_cast<_Float16*>(B + node)[n] = (_Float16)acc1[reg];
            }
        }
    }
}

// ============================================================================
// K2: per-edge MLP -> exp -> segment-sum. TWO edges per thread (e, e+E/2),
// sequential compute with the FULL load pipeline for both edges issued up
// front: edge-1's random gathers (A/B/deg) stay in flight (vmcnt>0) while
// edge-0's ~370-instr MLP runs -> 2x memory-level parallelism per wave.
// R3-R6 lesson: the old 2-edge attempt spilled because both edges' x[17]+
// acc[17] were live at once under a 64-VGPR cap. Here only raw inputs
// (a1,b1,v1,d1 ~ 20 VGPR) persist through edge-0's eval, and
// __launch_bounds__(256,4) allows up to 128 VGPR so regalloc need not spill.
// Weights in LDS (stride-20 rows, 16B-aligned). Softmax max-pass removed:
// identical ratios; |e_val| <~ 15 (fp32-safe).
// ============================================================================
__global__ __launch_bounds__(256, 4) void edge_mlp(
    const int* __restrict__ ind, const float* __restrict__ val,
    const H16* __restrict__ A, const H16* __restrict__ B,
    const float* __restrict__ deg,
    const float* __restrict__ W2, const float* __restrict__ b2,
    const float* __restrict__ Wc, const float* __restrict__ bc,
    float* __restrict__ eout, float* __restrict__ ssum, int E)
{
    __shared__ float w2s[L2DIM * 20];   // row c at w2s[c*20], 16B-aligned
    __shared__ float b2s[L2DIM];
    __shared__ float wcs[L2DIM];
    __shared__ float bc0s;

    const int t = threadIdx.x;
    for (int idx = t; idx < L2DIM * L2DIM; idx += 256) {
        int c = idx / L2DIM, r = idx - c * L2DIM;
        w2s[c * 20 + r] = W2[idx];
    }
    if (t < L2DIM) b2s[t] = b2[t];
    if (t < L2DIM) wcs[t] = Wc[t];
    if (t == 0)    bc0s   = bc[0];
    __syncthreads();

    const int E2 = (E + 1) >> 1;          // pair stride
    const int p  = blockIdx.x * 256 + t;
    if (p >= E2) return;

    const int  e0   = p;
    const int  e1   = p + E2;
    const bool has1 = (e1 < E);
    const int  e1s  = has1 ? e1 : e0;     // safe clone address for tail

    // ---- issue the full load pipeline for both edges up front ----
    int   i0 = ind[e0];        int j0 = ind[E + e0];
    int   i1 = ind[e1s];       int j1 = ind[E + e1s];
    H16   a0 = A[i0];          H16 b0 = B[j0];       // random 32B gathers
    float v0 = val[e0];        float d0 = deg[i0];
    H16   a1 = A[i1];          H16 b1 = B[j1];
    float v1 = val[e1s];       float d1 = deg[i1];

    auto eval = [&](const H16& a, const H16& bb, float v, float dg) -> float {
        float x[L2DIM];
#pragma unroll
        for (int q = 0; q < 8; ++q) {
            float2 fa = __half22float2(a.h[q]);
            float2 fb = __half22float2(bb.h[q]);
            x[2 * q]     = lrelu(fa.x + fb.x);       // b1 pre-folded into A
            x[2 * q + 1] = lrelu(fa.y + fb.y);
        }
        x[L1OUT] = fabsf(v) / dg;

        float acc[L2DIM];
#pragma unroll
        for (int r = 0; r < L2DIM; ++r) acc[r] = b2s[r];
#pragma unroll
        for (int c = 0; c < L2DIM; ++c) {
            float xc = x[c];
            const float4* r4 = reinterpret_cast<const float4*>(&w2s[c * 20]);
            float4 w0 = r4[0], w1v = r4[1], w2v = r4[2], w3 = r4[3];
            float  w16 = w2s[c * 20 + 16];
            acc[0]  += xc * w0.x;  acc[1]  += xc * w0.y;
            acc[2]  += xc * w0.z;  acc[3]  += xc * w0.w;
            acc[4]  += xc * w1v.x; acc[5]  += xc * w1v.y;
            acc[6]  += xc * w1v.z; acc[7]  += xc * w1v.w;
            acc[8]  += xc * w2v.x; acc[9]  += xc * w2v.y;
            acc[10] += xc * w2v.z; acc[11] += xc * w2v.w;
            acc[12] += xc * w3.x;  acc[13] += xc * w3.y;
            acc[14] += xc * w3.z;  acc[15] += xc * w3.w;
            acc[16] += xc * w16;
        }
        float ev = bc0s;
#pragma unroll
        for (int r = 0; r < L2DIM; ++r) ev += lrelu(acc[r]) * wcs[r];
        return __expf(ev);
    };

    // edge 0: its loads are the oldest in the vmcnt queue -> ready first;
    // a1/b1/d1 remain in flight underneath this compute.
    float ex0 = eval(a0, b0, v0, d0);
    eout[e0] = ex0;
    atomicAdd(&ssum[i0], ex0);

    if (has1) {
        float ex1 = eval(a1, b1, v1, d1);
        eout[e1] = ex1;
        atomicAdd(&ssum[i1], ex1);
    }
}

// ============================================================================
// K3: out = ex / s[i], 4 edges/thread vectorized
// ============================================================================
__global__ void normalize(const int* __restrict__ ind_i, const float* __restrict__ ssum,
                          float* __restrict__ ex, int E) {
    int t = blockIdx.x * blockDim.x + threadIdx.x;
    int e = t * 4;
    if (e + 3 < E) {
        int4   ii = *reinterpret_cast<const int4*>(ind_i + e);
        float4 vv = *reinterpret_cast<const float4*>(ex + e);
        vv.x /= ssum[ii.x];
        vv.y /= ssum[ii.y];
        vv.z /= ssum[ii.z];
        vv.w /= ssum[ii.w];
        *reinterpret_cast<float4*>(ex + e) = vv;
    } else {
        for (; e < E; ++e) ex[e] = ex[e] / ssum[ind_i[e]];
    }
}

extern "C" void kernel_launch(void* const* d_in, const int* in_sizes, int n_in,
                              void* d_out, int out_size, void* d_ws, size_t ws_size,
                              hipStream_t stream) {
    const int*   Jt_ind = (const int*)  d_in[0];   // [2,E]
    const float* Jt_val = (const float*)d_in[1];   // [E]
    const float* f      = (const float*)d_in[2];   // [N,128]
    const float* W1 = (const float*)d_in[4];       // [256,16]
    const float* b1 = (const float*)d_in[5];       // [16]
    const float* W2 = (const float*)d_in[6];       // [17,17]
    const float* b2 = (const float*)d_in[7];       // [17]
    const float* Wc = (const float*)d_in[8];       // [17,1]
    const float* bc = (const float*)d_in[9];       // [1]

    const int E = in_sizes[1];
    const int N = in_sizes[2] / FDIM;
    float* out = (float*)d_out;                    // [E] fp32

    // workspace: deg[N] | ssum[N] (contiguous -> one memset) | A[N] | B[N]
    char* ws = (char*)d_ws;
    float* deg  = (float*)ws;  ws += (size_t)N * sizeof(float);
    float* ssum = (float*)ws;  ws += (size_t)N * sizeof(float);
    H16*   A    = (H16*)ws;    ws += (size_t)N * sizeof(H16);
    H16*   Bm   = (H16*)ws;    ws += (size_t)N * sizeof(H16);

    const int B256 = 256;
    const int nblk = (N + TRM - 1) / TRM;                   // node tiles (128 rows)
    const int E2   = (E + 1) / 2;                           // edge pairs
    const int eblk = (E2 + B256 - 1) / B256;                // 2 edges/thread
    const int qblk = ((E + 3) / 4 + B256 - 1) / B256;       // 4 edges/thread

    hipMemsetAsync(deg, 0, 2 * (size_t)N * sizeof(float), stream);
    node_transform<<<nblk, B256, 0, stream>>>(f, W1, b1, Jt_ind, Jt_val,
                                              A, Bm, deg, N, E);
    edge_mlp      <<<eblk, B256, 0, stream>>>(Jt_ind, Jt_val, A, Bm, deg,
                                              W2, b2, Wc, bc, out, ssum, E);
    normalize     <<<qblk, B256, 0, stream>>>(Jt_ind, ssum, out, E);
}

// Round 2
// 209.601 us; speedup vs baseline: 2.4566x; 2.4566x over previous
//
#include <hip/hip_runtime.h>
#include <hip/hip_fp16.h>
#include <math.h>

#define FDIM  128
#define L1OUT 16
#define L2DIM 17
#define TRM   128     // f-rows per block in node_transform (MFMA version)
#define HSTR  136     // LDS tile row stride in halves (272 B: 2-way-only conflicts)

typedef _Float16 f16x8 __attribute__((ext_vector_type(8)));   // MFMA A/B frag (4 VGPR)
typedef float    f32x4 __attribute__((ext_vector_type(4)));   // MFMA C/D frag

// one 32-byte fp16 node row (16 halves); align 16 -> 2x global_load_dwordx4
struct __align__(16) H16 { __half2 h[8]; };

__device__ __forceinline__ float lrelu(float v) { return v >= 0.f ? v : 0.1f * v; }

// ============================================================================
// K1 (MFMA): [A|B] = f @ W'  where W'[k][c] = W1[k][c] (c<16) / W1[128+k][c-16].
// M=100k, K=128, N=32 -> mfma_f32_16x16x32_f16, 2 N-tiles (nt=0 -> A, 1 -> B).
// R8 lesson: VALU version needs 256 uniform ds_read_b128/wave for W1 (~35 us
// LDS-pipe floor). MFMA holds W' frags in 32 VGPRs (loaded once/block from
// L2-hot W1) and reads f-frags as 8 ds_read_b128/wave/subtile -> ~20x fewer
// LDS ops. f staged as fp16 (A/B outputs were already fp16; error budget ok).
// Layouts (HW-verified per guide): A-frag A[m=lane&15][k=(lane>>4)*8+j];
// B-frag B[k=(lane>>4)*8+j][n=lane&15]; C/D col=lane&15, row=(lane>>4)*4+reg.
// + degree atomics folded in (deg zeroed by memsetAsync before this kernel).
// ============================================================================
__global__ void node_transform(
    const float* __restrict__ f, const float* __restrict__ W1,
    const float* __restrict__ b1,
    const int* __restrict__ ind_i, const float* __restrict__ val,
    H16* __restrict__ A, H16* __restrict__ B,
    float* __restrict__ deg, int N, int E)
{
    __shared__ __align__(16) _Float16 tile[TRM * HSTR];   // 34.8 KB

    const int t    = threadIdx.x;
    const int gtid = blockIdx.x * 256 + t;
    const int GT   = gridDim.x * 256;

    // ---- degree atomics (4 edges/thread, grid-stride, fire-and-forget) ----
    {
        const int E4 = E >> 2;
        for (int q = gtid; q < E4; q += GT) {
            int e = q << 2;
            int4   ii = *reinterpret_cast<const int4*>(ind_i + e);
            float4 vv = *reinterpret_cast<const float4*>(val + e);
            atomicAdd(&deg[ii.x], fabsf(vv.x));
            atomicAdd(&deg[ii.y], fabsf(vv.y));
            atomicAdd(&deg[ii.z], fabsf(vv.z));
            atomicAdd(&deg[ii.w], fabsf(vv.w));
        }
        if (gtid < (E & 3)) {
            int e = (E & ~3) + gtid;
            atomicAdd(&deg[ind_i[e]], fabsf(val[e]));
        }
    }

    const int lane = t & 63;
    const int wv   = t >> 6;          // wave 0..3
    const int n    = lane & 15;       // MFMA matrix-dim index (col)
    const int quad = lane >> 4;       // k-block / row-group selector

    // ---- load W' B-frags once per block: bfr[nt][ks], k = 32*ks + 8*quad + j
    f16x8 bfr[2][4];
#pragma unroll
    for (int nt = 0; nt < 2; ++nt)
#pragma unroll
        for (int ks = 0; ks < 4; ++ks) {
            f16x8 bf;
#pragma unroll
            for (int j = 0; j < 8; ++j) {
                int k = 32 * ks + 8 * quad + j;
                bf[j] = (_Float16)W1[(size_t)(nt * FDIM + k) * L1OUT + n];
            }
            bfr[nt][ks] = bf;
        }
    float b1v = b1[n];                // folded into nt=0 accumulator init

    // ---- stage 128 f-rows as fp16 into padded LDS tile (coalesced) ----
    const int base = blockIdx.x * TRM;
#pragma unroll
    for (int q = 0; q < 8; ++q) {
        int p  = t + 256 * q;         // half8-chunk index 0..2047
        int r  = p >> 4;              // 16 chunks per row
        int c8 = p & 15;              // chunk within row (8 halves)
        float4 lo = make_float4(0.f, 0.f, 0.f, 0.f);
        float4 hi = lo;
        if (base + r < N) {
            const float4* src = reinterpret_cast<const float4*>(
                f + (size_t)(base + r) * FDIM + c8 * 8);
            lo = src[0];
            hi = src[1];
        }
        f16x8 hx;
        hx[0] = (_Float16)lo.x; hx[1] = (_Float16)lo.y;
        hx[2] = (_Float16)lo.z; hx[3] = (_Float16)lo.w;
        hx[4] = (_Float16)hi.x; hx[5] = (_Float16)hi.y;
        hx[6] = (_Float16)hi.z; hx[7] = (_Float16)hi.w;
        *reinterpret_cast<f16x8*>(&tile[r * HSTR + c8 * 8]) = hx;
    }
    __syncthreads();

    // ---- compute: wave wv handles M-subtiles wv and wv+4 (16 rows each) ----
#pragma unroll
    for (int si = 0; si < 2; ++si) {
        const int m0 = (wv + 4 * si) * 16;
        f32x4 acc0 = { b1v, b1v, b1v, b1v };      // A-cols + b1
        f32x4 acc1 = { 0.f, 0.f, 0.f, 0.f };      // B-cols
#pragma unroll
        for (int ks = 0; ks < 4; ++ks) {
            // A-frag: row m0+n, k = 32*ks + 8*quad .. +7  (one ds_read_b128)
            f16x8 af = *reinterpret_cast<const f16x8*>(
                &tile[(m0 + n) * HSTR + 32 * ks + 8 * quad]);
            acc0 = __builtin_amdgcn_mfma_f32_16x16x32_f16(af, bfr[0][ks], acc0, 0, 0, 0);
            acc1 = __builtin_amdgcn_mfma_f32_16x16x32_f16(af, bfr[1][ks], acc1, 0, 0, 0);
        }
        // epilogue: D col = n, rows = m0 + quad*4 + reg
#pragma unroll
        for (int reg = 0; reg < 4; ++reg) {
            int node = base + m0 + quad * 4 + reg;
            if (node < N) {
                reinterpret_cast<_Float16*>(A + node)[n] = (_Float16)acc0[reg];
                reinterpret_cast<_Float16*>(B + node)[n] = (_Float16)acc1[reg];
            }
        }
    }
}

// ============================================================================
// K2: per-edge MLP -> exp -> segment-sum. TWO edges per thread (e, e+E/2):
// full load pipeline for both edges issued up front so edge-1's random
// gathers stay in flight (vmcnt>0) under edge-0's ~370-instr MLP.
// R1 lesson (this session): a lambda taking `const H16&` made the gather
// results ADDRESSABLE -> alloca -> scratch (672 MB WRITE_SIZE, 6x slower).
// This version has NO structs/references/functions in the hot path: gathers
// land in plain f16x8 vector locals, all array indices are compile-time
// (full unroll), MLP body duplicated via macro -> SROA keeps everything in
// VGPRs. Expected check: WRITE_SIZE ~28 MB, VGPR ~96-128, 0 scratch.
// Weights in LDS (stride-20 rows, 16B-aligned). Softmax max-pass removed:
// identical ratios; |e_val| <~ 15 (fp32-safe).
// ============================================================================
#define MLP_TAIL(X, EXOUT)                                                  \
    {                                                                       \
        float acc[L2DIM];                                                   \
        _Pragma("unroll")                                                   \
        for (int r = 0; r < L2DIM; ++r) acc[r] = b2s[r];                    \
        _Pragma("unroll")                                                   \
        for (int c = 0; c < L2DIM; ++c) {                                   \
            float xc = X[c];                                                \
            const float4* r4 = reinterpret_cast<const float4*>(&w2s[c * 20]); \
            float4 w0 = r4[0], w1v = r4[1], w2v = r4[2], w3 = r4[3];        \
            float  w16 = w2s[c * 20 + 16];                                  \
            acc[0]  += xc * w0.x;  acc[1]  += xc * w0.y;                    \
            acc[2]  += xc * w0.z;  acc[3]  += xc * w0.w;                    \
            acc[4]  += xc * w1v.x; acc[5]  += xc * w1v.y;                   \
            acc[6]  += xc * w1v.z; acc[7]  += xc * w1v.w;                   \
            acc[8]  += xc * w2v.x; acc[9]  += xc * w2v.y;                   \
            acc[10] += xc * w2v.z; acc[11] += xc * w2v.w;                   \
            acc[12] += xc * w3.x;  acc[13] += xc * w3.y;                    \
            acc[14] += xc * w3.z;  acc[15] += xc * w3.w;                    \
            acc[16] += xc * w16;                                            \
        }                                                                   \
        float ev = bc0s;                                                    \
        _Pragma("unroll")                                                   \
        for (int r = 0; r < L2DIM; ++r) ev += lrelu(acc[r]) * wcs[r];       \
        EXOUT = __expf(ev);                                                 \
    }

__global__ __launch_bounds__(256, 4) void edge_mlp(
    const int* __restrict__ ind, const float* __restrict__ val,
    const H16* __restrict__ A, const H16* __restrict__ B,
    const float* __restrict__ deg,
    const float* __restrict__ W2, const float* __restrict__ b2,
    const float* __restrict__ Wc, const float* __restrict__ bc,
    float* __restrict__ eout, float* __restrict__ ssum, int E)
{
    __shared__ float w2s[L2DIM * 20];   // row c at w2s[c*20], 16B-aligned
    __shared__ float b2s[L2DIM];
    __shared__ float wcs[L2DIM];
    __shared__ float bc0s;

    const int t = threadIdx.x;
    for (int idx = t; idx < L2DIM * L2DIM; idx += 256) {
        int c = idx / L2DIM, r = idx - c * L2DIM;
        w2s[c * 20 + r] = W2[idx];
    }
    if (t < L2DIM) b2s[t] = b2[t];
    if (t < L2DIM) wcs[t] = Wc[t];
    if (t == 0)    bc0s   = bc[0];
    __syncthreads();

    const int E2 = (E + 1) >> 1;          // pair stride
    const int p  = blockIdx.x * 256 + t;
    if (p >= E2) return;

    const int  e0   = p;
    const int  e1   = p + E2;
    const bool has1 = (e1 < E);
    const int  e1s  = has1 ? e1 : e0;     // safe clone address for tail

    // ---- issue the full load pipeline for both edges up front ----
    int i0 = ind[e0];   int j0 = ind[E + e0];
    int i1 = ind[e1s];  int j1 = ind[E + e1s];

    const f16x8* pA0 = reinterpret_cast<const f16x8*>(A + i0);
    const f16x8* pB0 = reinterpret_cast<const f16x8*>(B + j0);
    const f16x8* pA1 = reinterpret_cast<const f16x8*>(A + i1);
    const f16x8* pB1 = reinterpret_cast<const f16x8*>(B + j1);

    f16x8 a0lo = pA0[0], a0hi = pA0[1];   // 2x global_load_dwordx4 each
    f16x8 b0lo = pB0[0], b0hi = pB0[1];
    float v0   = val[e0];
    float d0   = deg[i0];
    f16x8 a1lo = pA1[0], a1hi = pA1[1];   // stay in flight under edge-0 MLP
    f16x8 b1lo = pB1[0], b1hi = pB1[1];
    float v1   = val[e1s];
    float d1   = deg[i1];

    // ---- edge 0 (its loads are oldest in the vmcnt queue -> ready first) ----
    {
        float x[L2DIM];
#pragma unroll
        for (int k = 0; k < 8; ++k) {
            x[k]     = lrelu((float)a0lo[k] + (float)b0lo[k]);   // b1 pre-folded into A
            x[k + 8] = lrelu((float)a0hi[k] + (float)b0hi[k]);
        }
        x[L1OUT] = fabsf(v0) / d0;
        float ex0;
        MLP_TAIL(x, ex0);
        eout[e0] = ex0;
        atomicAdd(&ssum[i0], ex0);
    }

    // ---- edge 1 ----
    if (has1) {
        float x[L2DIM];
#pragma unroll
        for (int k = 0; k < 8; ++k) {
            x[k]     = lrelu((float)a1lo[k] + (float)b1lo[k]);
            x[k + 8] = lrelu((float)a1hi[k] + (float)b1hi[k]);
        }
        x[L1OUT] = fabsf(v1) / d1;
        float ex1;
        MLP_TAIL(x, ex1);
        eout[e1] = ex1;
        atomicAdd(&ssum[i1], ex1);
    }
}

// ============================================================================
// K3: out = ex / s[i], 4 edges/thread vectorized
// ============================================================================
__global__ void normalize(const int* __restrict__ ind_i, const float* __restrict__ ssum,
                          float* __restrict__ ex, int E) {
    int t = blockIdx.x * blockDim.x + threadIdx.x;
    int e = t * 4;
    if (e + 3 < E) {
        int4   ii = *reinterpret_cast<const int4*>(ind_i + e);
        float4 vv = *reinterpret_cast<const float4*>(ex + e);
        vv.x /= ssum[ii.x];
        vv.y /= ssum[ii.y];
        vv.z /= ssum[ii.z];
        vv.w /= ssum[ii.w];
        *reinterpret_cast<float4*>(ex + e) = vv;
    } else {
        for (; e < E; ++e) ex[e] = ex[e] / ssum[ind_i[e]];
    }
}

extern "C" void kernel_launch(void* const* d_in, const int* in_sizes, int n_in,
                              void* d_out, int out_size, void* d_ws, size_t ws_size,
                              hipStream_t stream) {
    const int*   Jt_ind = (const int*)  d_in[0];   // [2,E]
    const float* Jt_val = (const float*)d_in[1];   // [E]
    const float* f      = (const float*)d_in[2];   // [N,128]
    const float* W1 = (const float*)d_in[4];       // [256,16]
    const float* b1 = (const float*)d_in[5];       // [16]
    const float* W2 = (const float*)d_in[6];       // [17,17]
    const float* b2 = (const float*)d_in[7];       // [17]
    const float* Wc = (const float*)d_in[8];       // [17,1]
    const float* bc = (const float*)d_in[9];       // [1]

    const int E = in_sizes[1];
    const int N = in_sizes[2] / FDIM;
    float* out = (float*)d_out;                    // [E] fp32

    // workspace: deg[N] | ssum[N] (contiguous -> one memset) | A[N] | B[N]
    char* ws = (char*)d_ws;
    float* deg  = (float*)ws;  ws += (size_t)N * sizeof(float);
    float* ssum = (float*)ws;  ws += (size_t)N * sizeof(float);
    H16*   A    = (H16*)ws;    ws += (size_t)N * sizeof(H16);
    H16*   Bm   = (H16*)ws;    ws += (size_t)N * sizeof(H16);

    const int B256 = 256;
    const int nblk = (N + TRM - 1) / TRM;                   // node tiles (128 rows)
    const int E2   = (E + 1) / 2;                           // edge pairs
    const int eblk = (E2 + B256 - 1) / B256;                // 2 edges/thread
    const int qblk = ((E + 3) / 4 + B256 - 1) / B256;       // 4 edges/thread

    hipMemsetAsync(deg, 0, 2 * (size_t)N * sizeof(float), stream);
    node_transform<<<nblk, B256, 0, stream>>>(f, W1, b1, Jt_ind, Jt_val,
                                              A, Bm, deg, N, E);
    edge_mlp      <<<eblk, B256, 0, stream>>>(Jt_ind, Jt_val, A, Bm, deg,
                                              W2, b2, Wc, bc, out, ssum, E);
    normalize     <<<qblk, B256, 0, stream>>>(Jt_ind, ssum, out, E);
}